// Round 1
// baseline (503.545 us; speedup 1.0000x reference)
//
#include <hip/hip_runtime.h>

#define N_NODES 50000
#define N_EDGES 800000
#define F 64

// ---------------- CSR build ----------------

__global__ void hist_kernel(const int* __restrict__ dst, int* __restrict__ deg, int n) {
    int e = blockIdx.x * blockDim.x + threadIdx.x;
    if (e < n) atomicAdd(&deg[dst[e]], 1);
}

// single-block inclusive scan over deg -> row_ptr[1..n], row_ptr[0]=0
__global__ void scan_kernel(const int* __restrict__ deg, int* __restrict__ row_ptr, int n) {
    __shared__ int s[1024];
    int carry = 0;
    if (threadIdx.x == 0) row_ptr[0] = 0;
    for (int base = 0; base < n; base += 1024) {
        int i = base + (int)threadIdx.x;
        int v = (i < n) ? deg[i] : 0;
        s[threadIdx.x] = v;
        __syncthreads();
        for (int off = 1; off < 1024; off <<= 1) {
            int t = (threadIdx.x >= (unsigned)off) ? s[threadIdx.x - off] : 0;
            __syncthreads();
            s[threadIdx.x] += t;
            __syncthreads();
        }
        if (i < n) row_ptr[i + 1] = s[threadIdx.x] + carry;
        carry += s[1023];   // chunk total (padded with zeros)
        __syncthreads();    // protect s[] before next iteration's write
    }
}

__global__ void copy_int_kernel(const int* __restrict__ a, int* __restrict__ b, int n) {
    int i = blockIdx.x * blockDim.x + threadIdx.x;
    if (i < n) b[i] = a[i];
}

__global__ void fill_kernel(const int* __restrict__ src, const int* __restrict__ dst,
                            int* __restrict__ cursor, int* __restrict__ csr_src, int n) {
    int e = blockIdx.x * blockDim.x + threadIdx.x;
    if (e < n) {
        int d = dst[e];
        int pos = atomicAdd(&cursor[d], 1);
        csr_src[pos] = src[e];
    }
}

// ---------------- aggregation: one wave per node, lane = feature ----------------

__global__ __launch_bounds__(256) void aggregate_kernel(
        const float* __restrict__ x, const int* __restrict__ row_ptr,
        const int* __restrict__ csr_src, float* __restrict__ agg, int n_nodes) {
    int wave = threadIdx.x >> 6;
    int lane = threadIdx.x & 63;
    int node = blockIdx.x * 4 + wave;
    if (node >= n_nodes) return;
    int beg = row_ptr[node], end = row_ptr[node + 1];
    float sum = 0.f;
    for (int i = beg; i < end; ++i) {
        int s = csr_src[i];
        sum += x[s * F + lane];
    }
    int deg = end - beg;
    float inv = (deg > 0) ? (1.0f / (float)deg) : 0.f;
    agg[node * F + lane] = sum * inv;
}

// ---------------- transform: out = [relu](x@Ws + agg@Wn + b) ----------------

__global__ __launch_bounds__(256) void transform_kernel(
        const float* __restrict__ x, const float* __restrict__ agg,
        const float* __restrict__ Ws, const float* __restrict__ Wn,
        const float* __restrict__ b, float* __restrict__ out,
        int n_nodes, int do_relu) {
    __shared__ float sWs[F * F];
    __shared__ float sWn[F * F];
    __shared__ float sx[4][F];
    __shared__ float sa[4][F];

    for (int i = threadIdx.x; i < F * F; i += 256) {
        sWs[i] = Ws[i];
        sWn[i] = Wn[i];
    }

    int local = threadIdx.x >> 6;   // node slot in block
    int j     = threadIdx.x & 63;   // output feature
    float bj_bias = b[j];
    int ntiles = (n_nodes + 3) / 4;

    for (int tile = blockIdx.x; tile < ntiles; tile += gridDim.x) {
        int node = tile * 4 + local;
        __syncthreads();   // protect sx/sa reuse (also covers W load on first pass)
        if (node < n_nodes) {
            sx[local][j] = x[node * F + j];
            sa[local][j] = agg[node * F + j];
        }
        __syncthreads();
        if (node < n_nodes) {
            float acc = bj_bias;
            #pragma unroll
            for (int k = 0; k < F; ++k) {
                acc += sx[local][k] * sWs[k * F + j] + sa[local][k] * sWn[k * F + j];
            }
            if (do_relu) acc = fmaxf(acc, 0.f);
            out[node * F + j] = acc;
        }
    }
}

// ---------------- layer 3: scalar output, aggregate AFTER projection ----------------

__global__ __launch_bounds__(256) void dot_kernel(
        const float* __restrict__ h, const float* __restrict__ Ws3,
        const float* __restrict__ Wn3, float* __restrict__ p,
        float* __restrict__ q, int n_nodes) {
    int wave = threadIdx.x >> 6;
    int lane = threadIdx.x & 63;
    int node = blockIdx.x * 4 + wave;
    if (node >= n_nodes) return;
    float v = h[node * F + lane];
    float a = v * Wn3[lane];
    float c = v * Ws3[lane];
    #pragma unroll
    for (int off = 32; off > 0; off >>= 1) {
        a += __shfl_down(a, off);
        c += __shfl_down(c, off);
    }
    if (lane == 0) { p[node] = a; q[node] = c; }
}

__global__ __launch_bounds__(256) void final_kernel(
        const int* __restrict__ row_ptr, const int* __restrict__ csr_src,
        const float* __restrict__ p, const float* __restrict__ q,
        const float* __restrict__ b3, float* __restrict__ out, int n_nodes) {
    int node = blockIdx.x * blockDim.x + threadIdx.x;
    if (node >= n_nodes) return;
    int beg = row_ptr[node], end = row_ptr[node + 1];
    float sum = 0.f;
    for (int i = beg; i < end; ++i) sum += p[csr_src[i]];
    int deg = end - beg;
    float inv = (deg > 0) ? (1.0f / (float)deg) : 0.f;
    out[node] = q[node] + sum * inv + b3[0];
}

// ---------------- launch ----------------

extern "C" void kernel_launch(void* const* d_in, const int* in_sizes, int n_in,
                              void* d_out, int out_size, void* d_ws, size_t ws_size,
                              hipStream_t stream) {
    const float* x   = (const float*)d_in[0];
    const int*   src = (const int*)d_in[1];
    const int*   dst = (const int*)d_in[2];
    const float* Ws1 = (const float*)d_in[3];
    const float* Wn1 = (const float*)d_in[4];
    const float* b1  = (const float*)d_in[5];
    const float* Ws2 = (const float*)d_in[6];
    const float* Wn2 = (const float*)d_in[7];
    const float* b2  = (const float*)d_in[8];
    const float* Ws3 = (const float*)d_in[9];
    const float* Wn3 = (const float*)d_in[10];
    const float* b3  = (const float*)d_in[11];
    float* out = (float*)d_out;

    char* ws = (char*)d_ws;
    size_t cur = 0;
    auto alloc = [&](size_t bytes) -> void* {
        void* p = ws + cur;
        cur += (bytes + 255) & ~(size_t)255;
        return p;
    };

    int*   deg     = (int*)  alloc(N_NODES * sizeof(int));
    int*   row_ptr = (int*)  alloc((N_NODES + 1) * sizeof(int));
    int*   cursor  = (int*)  alloc(N_NODES * sizeof(int));
    int*   csr_src = (int*)  alloc(N_EDGES * sizeof(int));
    float* agg     = (float*)alloc((size_t)N_NODES * F * sizeof(float));
    float* h1      = (float*)alloc((size_t)N_NODES * F * sizeof(float));
    float* h2      = (float*)alloc((size_t)N_NODES * F * sizeof(float));
    float* p       = (float*)alloc(N_NODES * sizeof(float));
    float* q       = (float*)alloc(N_NODES * sizeof(float));

    // CSR build (same graph reused by all 3 layers)
    hipMemsetAsync(deg, 0, N_NODES * sizeof(int), stream);
    hist_kernel<<<(N_EDGES + 255) / 256, 256, 0, stream>>>(dst, deg, N_EDGES);
    scan_kernel<<<1, 1024, 0, stream>>>(deg, row_ptr, N_NODES);
    copy_int_kernel<<<(N_NODES + 255) / 256, 256, 0, stream>>>(row_ptr, cursor, N_NODES);
    fill_kernel<<<(N_EDGES + 255) / 256, 256, 0, stream>>>(src, dst, cursor, csr_src, N_EDGES);

    int agg_grid = (N_NODES + 3) / 4;

    // layer 1
    aggregate_kernel<<<agg_grid, 256, 0, stream>>>(x, row_ptr, csr_src, agg, N_NODES);
    transform_kernel<<<3125, 256, 0, stream>>>(x, agg, Ws1, Wn1, b1, h1, N_NODES, 1);
    // layer 2
    aggregate_kernel<<<agg_grid, 256, 0, stream>>>(h1, row_ptr, csr_src, agg, N_NODES);
    transform_kernel<<<3125, 256, 0, stream>>>(h1, agg, Ws2, Wn2, b2, h2, N_NODES, 1);
    // layer 3 (project to scalar, then aggregate scalars)
    dot_kernel<<<agg_grid, 256, 0, stream>>>(h2, Ws3, Wn3, p, q, N_NODES);
    final_kernel<<<(N_NODES + 255) / 256, 256, 0, stream>>>(row_ptr, csr_src, p, q, b3, out, N_NODES);
}

// Round 2
// 311.157 us; speedup vs baseline: 1.6183x; 1.6183x over previous
//
#include <hip/hip_runtime.h>

#define N_NODES 50000
#define N_EDGES 800000
#define F 64
#define SCAN_BLOCKS ((N_NODES + 255) / 256)   // 196

// ---------------- CSR build ----------------

__global__ void hist_kernel(const int* __restrict__ dst, int* __restrict__ deg, int n) {
    int e = blockIdx.x * blockDim.x + threadIdx.x;
    if (e < n) atomicAdd(&deg[dst[e]], 1);
}

// Hierarchical scan, stage A: per-block inclusive scan + block totals
__global__ __launch_bounds__(256) void scan_a(const int* __restrict__ deg,
                                              int* __restrict__ local_scan,
                                              int* __restrict__ partials, int n) {
    int i = blockIdx.x * 256 + threadIdx.x;
    int lane = threadIdx.x & 63, wv = threadIdx.x >> 6;
    int v = (i < n) ? deg[i] : 0;
    int s = v;
    #pragma unroll
    for (int off = 1; off < 64; off <<= 1) {
        int t = __shfl_up(s, off);
        if (lane >= off) s += t;
    }
    __shared__ int wsum[4];
    if (lane == 63) wsum[wv] = s;
    __syncthreads();
    if (threadIdx.x == 0) {
        int a = 0;
        #pragma unroll
        for (int w = 0; w < 4; ++w) { int t = wsum[w]; wsum[w] = a; a += t; }
        partials[blockIdx.x] = a;
    }
    __syncthreads();
    s += wsum[wv];
    if (i < n) local_scan[i] = s;   // inclusive within block
}

// Stage B: exclusive scan of block totals (nb <= 256, single block)
__global__ __launch_bounds__(256) void scan_b(int* __restrict__ partials, int nb) {
    int i = threadIdx.x;
    int lane = threadIdx.x & 63, wv = threadIdx.x >> 6;
    int v = (i < nb) ? partials[i] : 0;
    int s = v;
    #pragma unroll
    for (int off = 1; off < 64; off <<= 1) {
        int t = __shfl_up(s, off);
        if (lane >= off) s += t;
    }
    __shared__ int wsum[4];
    if (lane == 63) wsum[wv] = s;
    __syncthreads();
    if (threadIdx.x == 0) {
        int a = 0;
        #pragma unroll
        for (int w = 0; w < 4; ++w) { int t = wsum[w]; wsum[w] = a; a += t; }
    }
    __syncthreads();
    s += wsum[wv];
    if (i < nb) partials[i] = s - v;   // exclusive
}

// Stage C: add block offsets; emit row_ptr and cursor (= row start) in one pass
__global__ __launch_bounds__(256) void scan_c(const int* __restrict__ local_scan,
                                              const int* __restrict__ partials,
                                              const int* __restrict__ deg,
                                              int* __restrict__ row_ptr,
                                              int* __restrict__ cursor, int n) {
    int i = blockIdx.x * 256 + threadIdx.x;
    if (i >= n) return;
    int fin = local_scan[i] + partials[blockIdx.x];
    row_ptr[i + 1] = fin;
    cursor[i] = fin - deg[i];
    if (i == 0) row_ptr[0] = 0;
}

__global__ void fill_kernel(const int* __restrict__ src, const int* __restrict__ dst,
                            int* __restrict__ cursor, int* __restrict__ csr_src, int n) {
    int e = blockIdx.x * blockDim.x + threadIdx.x;
    if (e < n) {
        int d = dst[e];
        int pos = atomicAdd(&cursor[d], 1);
        csr_src[pos] = src[e];
    }
}

// ---------------- aggregation: wave/node, 4 edge-groups x 16 lanes x float4 ----------------

__global__ __launch_bounds__(256) void aggregate_kernel(
        const float4* __restrict__ x4, const int* __restrict__ row_ptr,
        const int* __restrict__ csr_src, float4* __restrict__ agg4, int n_nodes) {
    int wave = threadIdx.x >> 6;
    int lane = threadIdx.x & 63;
    int node = blockIdx.x * 4 + wave;
    if (node >= n_nodes) return;
    int g   = lane >> 4;    // edge group 0..3 (independent gather chains)
    int sub = lane & 15;    // float4 index within the 64-float row
    int beg = row_ptr[node], end = row_ptr[node + 1];
    float4 s = make_float4(0.f, 0.f, 0.f, 0.f);
    for (int i = beg + g; i < end; i += 4) {
        int sn = csr_src[i];
        float4 v = x4[sn * 16 + sub];
        s.x += v.x; s.y += v.y; s.z += v.z; s.w += v.w;
    }
    // reduce the 4 edge-groups
    #pragma unroll
    for (int off = 16; off <= 32; off <<= 1) {
        s.x += __shfl_xor(s.x, off);
        s.y += __shfl_xor(s.y, off);
        s.z += __shfl_xor(s.z, off);
        s.w += __shfl_xor(s.w, off);
    }
    if (g == 0) {
        int deg = end - beg;
        float inv = (deg > 0) ? (1.0f / (float)deg) : 0.f;
        s.x *= inv; s.y *= inv; s.z *= inv; s.w *= inv;
        agg4[node * 16 + sub] = s;
    }
}

// ---------------- transform: out = [relu](x@Ws + agg@Wn + b) ----------------
// 256 threads = 16 node-slots x 16 float4-columns; W staged as float4 rows.

__global__ __launch_bounds__(256) void transform_kernel(
        const float4* __restrict__ x4, const float4* __restrict__ agg4,
        const float4* __restrict__ Ws4, const float4* __restrict__ Wn4,
        const float* __restrict__ b, float* __restrict__ out,
        int n_nodes, int do_relu) {
    __shared__ float4 sWs[F * 16];     // [k][j4] row-major, 16 KB
    __shared__ float4 sWn[F * 16];     // 16 KB
    __shared__ float  sx[16][F + 4];   // +4 pad: breaks stride-64 bank conflict
    __shared__ float  sa[16][F + 4];

    for (int i = threadIdx.x; i < F * 16; i += 256) {
        sWs[i] = Ws4[i];
        sWn[i] = Wn4[i];
    }

    int j4   = threadIdx.x & 15;   // which float4 of the output row
    int slot = threadIdx.x >> 4;   // node slot 0..15
    float4 bias = ((const float4*)b)[j4];
    int ntiles = (n_nodes + 15) / 16;

    for (int tile = blockIdx.x; tile < ntiles; tile += gridDim.x) {
        int node = tile * 16 + slot;
        __syncthreads();   // protect sx/sa reuse (first pass: covers W staging)
        if (node < n_nodes) {
            float4 vx = x4[node * 16 + j4];
            float4 va = agg4[node * 16 + j4];
            *(float4*)&sx[slot][j4 * 4] = vx;
            *(float4*)&sa[slot][j4 * 4] = va;
        }
        __syncthreads();
        if (node < n_nodes) {
            float4 acc = bias;
            #pragma unroll
            for (int k = 0; k < F; ++k) {
                float xv = sx[slot][k];
                float av = sa[slot][k];
                float4 ws = sWs[k * 16 + j4];
                float4 wn = sWn[k * 16 + j4];
                acc.x += xv * ws.x + av * wn.x;
                acc.y += xv * ws.y + av * wn.y;
                acc.z += xv * ws.z + av * wn.z;
                acc.w += xv * ws.w + av * wn.w;
            }
            if (do_relu) {
                acc.x = fmaxf(acc.x, 0.f); acc.y = fmaxf(acc.y, 0.f);
                acc.z = fmaxf(acc.z, 0.f); acc.w = fmaxf(acc.w, 0.f);
            }
            *(float4*)&out[node * F + j4 * 4] = acc;
        }
    }
}

// ---------------- layer 3: project to scalar, then aggregate scalars ----------------

__global__ __launch_bounds__(256) void dot_kernel(
        const float* __restrict__ h, const float* __restrict__ Ws3,
        const float* __restrict__ Wn3, float* __restrict__ p,
        float* __restrict__ q, int n_nodes) {
    int wave = threadIdx.x >> 6;
    int lane = threadIdx.x & 63;
    int node = blockIdx.x * 4 + wave;
    if (node >= n_nodes) return;
    float v = h[node * F + lane];
    float a = v * Wn3[lane];
    float c = v * Ws3[lane];
    #pragma unroll
    for (int off = 32; off > 0; off >>= 1) {
        a += __shfl_down(a, off);
        c += __shfl_down(c, off);
    }
    if (lane == 0) { p[node] = a; q[node] = c; }
}

__global__ __launch_bounds__(256) void final_kernel(
        const int* __restrict__ row_ptr, const int* __restrict__ csr_src,
        const float* __restrict__ p, const float* __restrict__ q,
        const float* __restrict__ b3, float* __restrict__ out, int n_nodes) {
    int node = blockIdx.x * blockDim.x + threadIdx.x;
    if (node >= n_nodes) return;
    int beg = row_ptr[node], end = row_ptr[node + 1];
    float sum = 0.f;
    for (int i = beg; i < end; ++i) sum += p[csr_src[i]];
    int deg = end - beg;
    float inv = (deg > 0) ? (1.0f / (float)deg) : 0.f;
    out[node] = q[node] + sum * inv + b3[0];
}

// ---------------- launch ----------------

extern "C" void kernel_launch(void* const* d_in, const int* in_sizes, int n_in,
                              void* d_out, int out_size, void* d_ws, size_t ws_size,
                              hipStream_t stream) {
    const float* x   = (const float*)d_in[0];
    const int*   src = (const int*)d_in[1];
    const int*   dst = (const int*)d_in[2];
    const float* Ws1 = (const float*)d_in[3];
    const float* Wn1 = (const float*)d_in[4];
    const float* b1  = (const float*)d_in[5];
    const float* Ws2 = (const float*)d_in[6];
    const float* Wn2 = (const float*)d_in[7];
    const float* b2  = (const float*)d_in[8];
    const float* Ws3 = (const float*)d_in[9];
    const float* Wn3 = (const float*)d_in[10];
    const float* b3  = (const float*)d_in[11];
    float* out = (float*)d_out;

    char* ws = (char*)d_ws;
    size_t cur = 0;
    auto alloc = [&](size_t bytes) -> void* {
        void* p = ws + cur;
        cur += (bytes + 255) & ~(size_t)255;
        return p;
    };

    int*   deg      = (int*)  alloc(N_NODES * sizeof(int));
    int*   lscan    = (int*)  alloc(N_NODES * sizeof(int));
    int*   partials = (int*)  alloc(256 * sizeof(int));
    int*   row_ptr  = (int*)  alloc((N_NODES + 1) * sizeof(int));
    int*   cursor   = (int*)  alloc(N_NODES * sizeof(int));
    int*   csr_src  = (int*)  alloc(N_EDGES * sizeof(int));
    float* agg      = (float*)alloc((size_t)N_NODES * F * sizeof(float));
    float* h1       = (float*)alloc((size_t)N_NODES * F * sizeof(float));
    float* h2       = (float*)alloc((size_t)N_NODES * F * sizeof(float));
    float* p        = (float*)alloc(N_NODES * sizeof(float));
    float* q        = (float*)alloc(N_NODES * sizeof(float));

    // CSR build
    hipMemsetAsync(deg, 0, N_NODES * sizeof(int), stream);
    hist_kernel<<<(N_EDGES + 255) / 256, 256, 0, stream>>>(dst, deg, N_EDGES);
    scan_a<<<SCAN_BLOCKS, 256, 0, stream>>>(deg, lscan, partials, N_NODES);
    scan_b<<<1, 256, 0, stream>>>(partials, SCAN_BLOCKS);
    scan_c<<<SCAN_BLOCKS, 256, 0, stream>>>(lscan, partials, deg, row_ptr, cursor, N_NODES);
    fill_kernel<<<(N_EDGES + 255) / 256, 256, 0, stream>>>(src, dst, cursor, csr_src, N_EDGES);

    int agg_grid = (N_NODES + 3) / 4;

    // layer 1
    aggregate_kernel<<<agg_grid, 256, 0, stream>>>(
        (const float4*)x, row_ptr, csr_src, (float4*)agg, N_NODES);
    transform_kernel<<<1024, 256, 0, stream>>>(
        (const float4*)x, (const float4*)agg, (const float4*)Ws1, (const float4*)Wn1,
        b1, h1, N_NODES, 1);
    // layer 2
    aggregate_kernel<<<agg_grid, 256, 0, stream>>>(
        (const float4*)h1, row_ptr, csr_src, (float4*)agg, N_NODES);
    transform_kernel<<<1024, 256, 0, stream>>>(
        (const float4*)h1, (const float4*)agg, (const float4*)Ws2, (const float4*)Wn2,
        b2, h2, N_NODES, 1);
    // layer 3
    dot_kernel<<<agg_grid, 256, 0, stream>>>(h2, Ws3, Wn3, p, q, N_NODES);
    final_kernel<<<(N_NODES + 255) / 256, 256, 0, stream>>>(row_ptr, csr_src, p, q, b3, out, N_NODES);
}

// Round 3
// 299.520 us; speedup vs baseline: 1.6812x; 1.0389x over previous
//
#include <hip/hip_runtime.h>

#define N_NODES 50000
#define N_EDGES 800000
#define F 64
#define SCAN_BLOCKS ((N_NODES + 255) / 256)   // 196
#define TSLOTS 64                              // nodes per transform tile

// ---------------- CSR build ----------------

__global__ void hist_kernel(const int* __restrict__ dst, int* __restrict__ deg, int n) {
    int e = blockIdx.x * blockDim.x + threadIdx.x;
    if (e < n) atomicAdd(&deg[dst[e]], 1);
}

__global__ __launch_bounds__(256) void scan_a(const int* __restrict__ deg,
                                              int* __restrict__ local_scan,
                                              int* __restrict__ partials, int n) {
    int i = blockIdx.x * 256 + threadIdx.x;
    int lane = threadIdx.x & 63, wv = threadIdx.x >> 6;
    int v = (i < n) ? deg[i] : 0;
    int s = v;
    #pragma unroll
    for (int off = 1; off < 64; off <<= 1) {
        int t = __shfl_up(s, off);
        if (lane >= off) s += t;
    }
    __shared__ int wsum[4];
    if (lane == 63) wsum[wv] = s;
    __syncthreads();
    if (threadIdx.x == 0) {
        int a = 0;
        #pragma unroll
        for (int w = 0; w < 4; ++w) { int t = wsum[w]; wsum[w] = a; a += t; }
        partials[blockIdx.x] = a;
    }
    __syncthreads();
    s += wsum[wv];
    if (i < n) local_scan[i] = s;
}

__global__ __launch_bounds__(256) void scan_b(int* __restrict__ partials, int nb) {
    int i = threadIdx.x;
    int lane = threadIdx.x & 63, wv = threadIdx.x >> 6;
    int v = (i < nb) ? partials[i] : 0;
    int s = v;
    #pragma unroll
    for (int off = 1; off < 64; off <<= 1) {
        int t = __shfl_up(s, off);
        if (lane >= off) s += t;
    }
    __shared__ int wsum[4];
    if (lane == 63) wsum[wv] = s;
    __syncthreads();
    if (threadIdx.x == 0) {
        int a = 0;
        #pragma unroll
        for (int w = 0; w < 4; ++w) { int t = wsum[w]; wsum[w] = a; a += t; }
    }
    __syncthreads();
    s += wsum[wv];
    if (i < nb) partials[i] = s - v;
}

__global__ __launch_bounds__(256) void scan_c(const int* __restrict__ local_scan,
                                              const int* __restrict__ partials,
                                              const int* __restrict__ deg,
                                              int* __restrict__ row_ptr,
                                              int* __restrict__ cursor, int n) {
    int i = blockIdx.x * 256 + threadIdx.x;
    if (i >= n) return;
    int fin = local_scan[i] + partials[blockIdx.x];
    row_ptr[i + 1] = fin;
    cursor[i] = fin - deg[i];
    if (i == 0) row_ptr[0] = 0;
}

__global__ void fill_kernel(const int* __restrict__ src, const int* __restrict__ dst,
                            int* __restrict__ cursor, unsigned short* __restrict__ csr16, int n) {
    int e = blockIdx.x * blockDim.x + threadIdx.x;
    if (e < n) {
        int d = dst[e];
        int pos = atomicAdd(&cursor[d], 1);
        csr16[pos] = (unsigned short)src[e];   // src < 50000 < 65536
    }
}

// ---------------- aggregation: wave/node, 4 groups x float4, 2-deep unroll ----------------

__global__ __launch_bounds__(256) void aggregate_kernel(
        const float4* __restrict__ x4, const int* __restrict__ row_ptr,
        const unsigned short* __restrict__ csr16, float4* __restrict__ agg4, int n_nodes) {
    int wave = threadIdx.x >> 6;
    int lane = threadIdx.x & 63;
    int node = blockIdx.x * 4 + wave;
    if (node >= n_nodes) return;
    int g   = lane >> 4;
    int sub = lane & 15;
    int beg = row_ptr[node], end = row_ptr[node + 1];
    float4 s0 = make_float4(0.f, 0.f, 0.f, 0.f);
    float4 s1 = make_float4(0.f, 0.f, 0.f, 0.f);
    int i = beg + g;
    for (; i + 4 < end; i += 8) {
        int a = csr16[i];
        int b = csr16[i + 4];
        float4 v0 = x4[a * 16 + sub];
        float4 v1 = x4[b * 16 + sub];
        s0.x += v0.x; s0.y += v0.y; s0.z += v0.z; s0.w += v0.w;
        s1.x += v1.x; s1.y += v1.y; s1.z += v1.z; s1.w += v1.w;
    }
    if (i < end) {
        float4 v0 = x4[csr16[i] * 16 + sub];
        s0.x += v0.x; s0.y += v0.y; s0.z += v0.z; s0.w += v0.w;
    }
    float4 s = make_float4(s0.x + s1.x, s0.y + s1.y, s0.z + s1.z, s0.w + s1.w);
    #pragma unroll
    for (int off = 16; off <= 32; off <<= 1) {
        s.x += __shfl_xor(s.x, off);
        s.y += __shfl_xor(s.y, off);
        s.z += __shfl_xor(s.z, off);
        s.w += __shfl_xor(s.w, off);
    }
    if (g == 0) {
        int deg = end - beg;
        float inv = (deg > 0) ? (1.0f / (float)deg) : 0.f;
        s.x *= inv; s.y *= inv; s.z *= inv; s.w *= inv;
        agg4[node * 16 + sub] = s;
    }
}

// ---------------- transform: 64-node tiles, 4 nodes/thread; optional fused L3 projection ----
// thread = (sg = tid>>4: 16 slot-groups) x (j4 = tid&15: float4 output column)
// if pout != null: h = relu(conv2) is NOT stored; instead p = h . Wn3, q = h . Ws3.

__global__ __launch_bounds__(256) void transform_kernel(
        const float4* __restrict__ x4, const float4* __restrict__ agg4,
        const float4* __restrict__ Ws4, const float4* __restrict__ Wn4,
        const float* __restrict__ b, float* __restrict__ out,
        int n_nodes, int do_relu,
        const float* __restrict__ Ws3, const float* __restrict__ Wn3,
        float* __restrict__ pout, float* __restrict__ qout) {
    __shared__ float4 sWs[F * 16];       // 16 KB
    __shared__ float4 sWn[F * 16];       // 16 KB
    __shared__ float  sx[TSLOTS][F + 4]; // 17.4 KB (pad 4: conflict-free per 32-lane phase)
    __shared__ float  sa[TSLOTS][F + 4];

    for (int i = threadIdx.x; i < F * 16; i += 256) {
        sWs[i] = Ws4[i];
        sWn[i] = Wn4[i];
    }

    int j4 = threadIdx.x & 15;
    int sg = threadIdx.x >> 4;
    float4 bias = ((const float4*)b)[j4];
    float4 w3n = make_float4(0.f, 0.f, 0.f, 0.f);
    float4 w3s = make_float4(0.f, 0.f, 0.f, 0.f);
    if (pout) {
        w3n = ((const float4*)Wn3)[j4];
        w3s = ((const float4*)Ws3)[j4];
    }
    int ntiles = (n_nodes + TSLOTS - 1) / TSLOTS;

    for (int tile = blockIdx.x; tile < ntiles; tile += gridDim.x) {
        int base = tile * TSLOTS;
        __syncthreads();   // protect sx/sa reuse (first pass also covers W staging)
        for (int t = threadIdx.x; t < TSLOTS * 16; t += 256) {
            int slot = t >> 4, c = t & 15;
            int node = base + slot;
            float4 vx = make_float4(0.f, 0.f, 0.f, 0.f);
            float4 va = vx;
            if (node < n_nodes) { vx = x4[node * 16 + c]; va = agg4[node * 16 + c]; }
            *(float4*)&sx[slot][c * 4] = vx;
            *(float4*)&sa[slot][c * 4] = va;
        }
        __syncthreads();

        float4 acc[4];
        #pragma unroll
        for (int s = 0; s < 4; ++s) acc[s] = bias;
        #pragma unroll
        for (int k = 0; k < F; ++k) {
            float4 ws = sWs[k * 16 + j4];
            float4 wn = sWn[k * 16 + j4];
            #pragma unroll
            for (int s = 0; s < 4; ++s) {
                float xv = sx[sg * 4 + s][k];
                float av = sa[sg * 4 + s][k];
                acc[s].x += xv * ws.x + av * wn.x;
                acc[s].y += xv * ws.y + av * wn.y;
                acc[s].z += xv * ws.z + av * wn.z;
                acc[s].w += xv * ws.w + av * wn.w;
            }
        }

        if (pout) {
            // relu then project to scalars; reduce across the 16 j4 lanes (same wave,
            // contiguous lanes since group = sg covers lanes sg*16..sg*16+15 mod 64)
            #pragma unroll
            for (int s = 0; s < 4; ++s) {
                int node = base + sg * 4 + s;
                if (node < n_nodes) {  // uniform across the 16-lane group
                    float4 h;
                    h.x = fmaxf(acc[s].x, 0.f); h.y = fmaxf(acc[s].y, 0.f);
                    h.z = fmaxf(acc[s].z, 0.f); h.w = fmaxf(acc[s].w, 0.f);
                    float pp = h.x * w3n.x + h.y * w3n.y + h.z * w3n.z + h.w * w3n.w;
                    float qq = h.x * w3s.x + h.y * w3s.y + h.z * w3s.z + h.w * w3s.w;
                    #pragma unroll
                    for (int off = 1; off < 16; off <<= 1) {
                        pp += __shfl_xor(pp, off);
                        qq += __shfl_xor(qq, off);
                    }
                    if (j4 == 0) { pout[node] = pp; qout[node] = qq; }
                }
            }
        } else {
            #pragma unroll
            for (int s = 0; s < 4; ++s) {
                int node = base + sg * 4 + s;
                if (node < n_nodes) {
                    float4 v = acc[s];
                    if (do_relu) {
                        v.x = fmaxf(v.x, 0.f); v.y = fmaxf(v.y, 0.f);
                        v.z = fmaxf(v.z, 0.f); v.w = fmaxf(v.w, 0.f);
                    }
                    *(float4*)&out[node * F + j4 * 4] = v;
                }
            }
        }
    }
}

// ---------------- final: out = q + mean_agg(p) + b3, 16 lanes per node ----------------

__global__ __launch_bounds__(256) void final_kernel(
        const int* __restrict__ row_ptr, const unsigned short* __restrict__ csr16,
        const float* __restrict__ p, const float* __restrict__ q,
        const float* __restrict__ b3, float* __restrict__ out, int n_nodes) {
    int grp = threadIdx.x >> 4;
    int ln  = threadIdx.x & 15;
    int node = blockIdx.x * 16 + grp;
    if (node >= n_nodes) return;
    int beg = row_ptr[node], end = row_ptr[node + 1];
    float s = 0.f;
    for (int i = beg + ln; i < end; i += 16) s += p[csr16[i]];
    #pragma unroll
    for (int off = 1; off < 16; off <<= 1) s += __shfl_xor(s, off);
    if (ln == 0) {
        int deg = end - beg;
        float inv = (deg > 0) ? (1.0f / (float)deg) : 0.f;
        out[node] = q[node] + s * inv + b3[0];
    }
}

// ---------------- launch ----------------

extern "C" void kernel_launch(void* const* d_in, const int* in_sizes, int n_in,
                              void* d_out, int out_size, void* d_ws, size_t ws_size,
                              hipStream_t stream) {
    const float* x   = (const float*)d_in[0];
    const int*   src = (const int*)d_in[1];
    const int*   dst = (const int*)d_in[2];
    const float* Ws1 = (const float*)d_in[3];
    const float* Wn1 = (const float*)d_in[4];
    const float* b1  = (const float*)d_in[5];
    const float* Ws2 = (const float*)d_in[6];
    const float* Wn2 = (const float*)d_in[7];
    const float* b2  = (const float*)d_in[8];
    const float* Ws3 = (const float*)d_in[9];
    const float* Wn3 = (const float*)d_in[10];
    const float* b3  = (const float*)d_in[11];
    float* out = (float*)d_out;

    char* ws = (char*)d_ws;
    size_t cur = 0;
    auto alloc = [&](size_t bytes) -> void* {
        void* p = ws + cur;
        cur += (bytes + 255) & ~(size_t)255;
        return p;
    };

    int*            deg      = (int*)  alloc(N_NODES * sizeof(int));
    int*            lscan    = (int*)  alloc(N_NODES * sizeof(int));
    int*            partials = (int*)  alloc(256 * sizeof(int));
    int*            row_ptr  = (int*)  alloc((N_NODES + 1) * sizeof(int));
    int*            cursor   = (int*)  alloc(N_NODES * sizeof(int));
    unsigned short* csr16    = (unsigned short*)alloc(N_EDGES * sizeof(unsigned short));
    float*          agg      = (float*)alloc((size_t)N_NODES * F * sizeof(float));
    float*          h1       = (float*)alloc((size_t)N_NODES * F * sizeof(float));
    float*          p        = (float*)alloc(N_NODES * sizeof(float));
    float*          q        = (float*)alloc(N_NODES * sizeof(float));

    // CSR build
    hipMemsetAsync(deg, 0, N_NODES * sizeof(int), stream);
    hist_kernel<<<(N_EDGES + 255) / 256, 256, 0, stream>>>(dst, deg, N_EDGES);
    scan_a<<<SCAN_BLOCKS, 256, 0, stream>>>(deg, lscan, partials, N_NODES);
    scan_b<<<1, 256, 0, stream>>>(partials, SCAN_BLOCKS);
    scan_c<<<SCAN_BLOCKS, 256, 0, stream>>>(lscan, partials, deg, row_ptr, cursor, N_NODES);
    fill_kernel<<<(N_EDGES + 255) / 256, 256, 0, stream>>>(src, dst, cursor, csr16, N_EDGES);

    int agg_grid = (N_NODES + 3) / 4;
    int tf_grid  = (N_NODES + TSLOTS - 1) / TSLOTS;   // 782

    // layer 1
    aggregate_kernel<<<agg_grid, 256, 0, stream>>>(
        (const float4*)x, row_ptr, csr16, (float4*)agg, N_NODES);
    transform_kernel<<<tf_grid, 256, 0, stream>>>(
        (const float4*)x, (const float4*)agg, (const float4*)Ws1, (const float4*)Wn1,
        b1, h1, N_NODES, 1, nullptr, nullptr, nullptr, nullptr);
    // layer 2 (+ fused layer-3 projection: p = relu(conv2) . Wn3, q = . Ws3)
    aggregate_kernel<<<agg_grid, 256, 0, stream>>>(
        (const float4*)h1, row_ptr, csr16, (float4*)agg, N_NODES);
    transform_kernel<<<tf_grid, 256, 0, stream>>>(
        (const float4*)h1, (const float4*)agg, (const float4*)Ws2, (const float4*)Wn2,
        b2, nullptr, N_NODES, 1, Ws3, Wn3, p, q);
    // layer 3: aggregate scalars
    final_kernel<<<(N_NODES + 15) / 16, 256, 0, stream>>>(row_ptr, csr16, p, q, b3, out, N_NODES);
}